// Round 10
// baseline (65.654 us; speedup 1.0000x reference)
//
#include <hip/hip_runtime.h>
#include <math.h>

#define N0 2048
#define N1 1024
#define M0T 32                     // 2048 / 64-row tiles
#define M1T 32                     // 1024 / 32-row tiles
#define NB0 (M0T * (M0T + 1) / 2)  // 528 lower-tri tile pairs, layer 0 (64x64)
#define NB1 (M1T * (M1T + 1) / 2)  // 528 lower-tri tile pairs, layer 1 (32x32)
#define NBTOT (NB0 + NB1)          // 1056 blocks

// ws layout (floats): partial[NBTOT] only.
//
// Ledger:
// R1: same-address f64 atomics+fence serialized 2112 blocks -> separate
//     finalize kernel. Counter relic: VGPR_Count=40 (!) for a kernel with
//     ~50 live floats -> compiler starved registers for occupancy.
// R2/R4: window = fill(39.5, harness ws-poison, fixed) + rest. Dispatch-count
//     changes (3->2) were NET ZERO -> boundaries are cheap; kernel time rules.
// R7: un-split tiles + drop 5x5 Newton: 69.9 -> 65.4, absmax 0.
//     Inferred pairs ~20-23us vs ~3us issue floor -> huge stall factor.
// R9: cooperative single-kernel FAILED absmax (4.5e-6): plain stores to
//     partial[] not coherent across XCDs despite threadfence+grid.sync.
//     Kernel boundary IS the coherence mechanism. Coop design dead.
// R10 (this): R7 skeleton + __launch_bounds__(256,2) (VGPR cap 256; stop the
//     spill/LDS-refold of a[4][9]/b[9]/a[2][25]) + L1 prep split so inv5
//     (wave 0) and norm5 (wave 1) don't serialize under divergence.
//     Predict 65.4 -> ~58-62us, absmax 0.

__device__ __forceinline__ void tri_decode(int t, int& bi, int& bj) {
    int b = (int)((sqrtf(8.0f * t + 1.0f) - 1.0f) * 0.5f);
    while ((b + 1) * (b + 2) / 2 <= t) ++b;
    while (b * (b + 1) / 2 > t) --b;
    bi = b;
    bj = t - b * (b + 1) / 2;
}

// normalize + adjugate inverse + 1 Newton polish, 3x3, fp32 (cheap, keep polish)
__device__ __forceinline__ void inv3_to(const float* __restrict__ g, float* __restrict__ dst) {
    float a[9];
    float ss = 0.0f;
#pragma unroll
    for (int e = 0; e < 9; ++e) { a[e] = g[e]; ss = fmaf(a[e], a[e], ss); }
    float rn = 1.0f / (sqrtf(ss) + 1e-8f);
#pragma unroll
    for (int e = 0; e < 9; ++e) a[e] *= rn;
    float c00 = a[4] * a[8] - a[5] * a[7];
    float c01 = -(a[3] * a[8] - a[5] * a[6]);
    float c02 = a[3] * a[7] - a[4] * a[6];
    float det = a[0] * c00 + a[1] * c01 + a[2] * c02;
    float id = 1.0f / det;
    float x[9];
    x[0] = c00 * id;
    x[1] = (a[2] * a[7] - a[1] * a[8]) * id;
    x[2] = (a[1] * a[5] - a[2] * a[4]) * id;
    x[3] = c01 * id;
    x[4] = (a[0] * a[8] - a[2] * a[6]) * id;
    x[5] = (a[2] * a[3] - a[0] * a[5]) * id;
    x[6] = c02 * id;
    x[7] = (a[1] * a[6] - a[0] * a[7]) * id;
    x[8] = (a[0] * a[4] - a[1] * a[3]) * id;
    // Newton polish: x <- x(2I - a x)
    float r[9];
#pragma unroll
    for (int i = 0; i < 3; ++i)
#pragma unroll
        for (int j = 0; j < 3; ++j) {
            float m = a[i * 3 + 0] * x[0 * 3 + j];
            m = fmaf(a[i * 3 + 1], x[1 * 3 + j], m);
            m = fmaf(a[i * 3 + 2], x[2 * 3 + j], m);
            r[i * 3 + j] = ((i == j) ? 2.0f : 0.0f) - m;
        }
#pragma unroll
    for (int i = 0; i < 3; ++i)
#pragma unroll
        for (int j = 0; j < 3; ++j) {
            float m = x[i * 3 + 0] * r[0 * 3 + j];
            m = fmaf(x[i * 3 + 1], r[1 * 3 + j], m);
            m = fmaf(x[i * 3 + 2], r[2 * 3 + j], m);
            dst[i * 3 + j] = m;
        }
}

// normalize only, 3x3
__device__ __forceinline__ void norm3_to(const float* __restrict__ g, float* __restrict__ dst) {
    float a[9];
    float ss = 0.0f;
#pragma unroll
    for (int e = 0; e < 9; ++e) { a[e] = g[e]; ss = fmaf(a[e], a[e], ss); }
    float rn = 1.0f / (sqrtf(ss) + 1e-8f);
#pragma unroll
    for (int e = 0; e < 9; ++e) dst[e] = a[e] * rn;
}

// normalize + branchless GJ w/ partial pivot, 5x5, fp32 (no Newton; R7-verified)
__device__ __forceinline__ void inv5_to(const float* __restrict__ g, float* __restrict__ dst) {
    float A[5][5], B[5][5];
    float ss = 0.0f;
#pragma unroll
    for (int r = 0; r < 5; ++r)
#pragma unroll
        for (int c = 0; c < 5; ++c) {
            float v = g[r * 5 + c];
            A[r][c] = v;
            ss = fmaf(v, v, ss);
        }
    float rn = 1.0f / (sqrtf(ss) + 1e-8f);
#pragma unroll
    for (int r = 0; r < 5; ++r)
#pragma unroll
        for (int c = 0; c < 5; ++c) {
            A[r][c] *= rn;
            B[r][c] = (r == c) ? 1.0f : 0.0f;
        }
#pragma unroll
    for (int k = 0; k < 5; ++k) {
#pragma unroll
        for (int r = k + 1; r < 5; ++r) {
            bool sw = fabsf(A[r][k]) > fabsf(A[k][k]);
#pragma unroll
            for (int c = k; c < 5; ++c) {
                float Ar = A[r][c], Ak = A[k][c];
                A[r][c] = sw ? Ak : Ar;
                A[k][c] = sw ? Ar : Ak;
            }
#pragma unroll
            for (int c = 0; c < 5; ++c) {
                float Br = B[r][c], Bk = B[k][c];
                B[r][c] = sw ? Bk : Br;
                B[k][c] = sw ? Br : Bk;
            }
        }
        float piv = 1.0f / A[k][k];
#pragma unroll
        for (int c = k; c < 5; ++c) A[k][c] *= piv;
#pragma unroll
        for (int c = 0; c < 5; ++c) B[k][c] *= piv;
#pragma unroll
        for (int r = 0; r < 5; ++r) {
            if (r == k) continue;
            float f = A[r][k];
#pragma unroll
            for (int c = k; c < 5; ++c) A[r][c] = fmaf(-f, A[k][c], A[r][c]);
#pragma unroll
            for (int c = 0; c < 5; ++c) B[r][c] = fmaf(-f, B[k][c], B[r][c]);
        }
    }
#pragma unroll
    for (int r = 0; r < 5; ++r)
#pragma unroll
        for (int c = 0; c < 5; ++c) dst[r * 5 + c] = B[r][c];
}

// normalize only, 5x5
__device__ __forceinline__ void norm5_to(const float* __restrict__ g, float* __restrict__ dst) {
    float a[25];
    float ss = 0.0f;
#pragma unroll
    for (int e = 0; e < 25; ++e) { a[e] = g[e]; ss = fmaf(a[e], a[e], ss); }
    float rn = 1.0f / (sqrtf(ss) + 1e-8f);
#pragma unroll
    for (int e = 0; e < 25; ++e) dst[e] = a[e] * rn;
}

// ---------------------------------------------------------------------------
// Fused prep + pair-distance kernel, FULL-tile triangular grid (R7 structure).
//   blocks [0, NB0):     layer 0 (d=3): 64x64 tile, 4x4 pairs/thread
//   blocks [NB0, NBTOT): layer 1 (d=5): 32x32 tile, 2x2 pairs/thread
// __launch_bounds__(256, 2): min 2 waves/EU -> VGPR cap 256. The default
// heuristic starved the kernel to 40 VGPR (R1 counter), forcing a[4][9]/b[9]
// (L0) and a[2][25]/b[25] (L1) out of registers into scratch/LDS-refold.
// ~100-128 VGPR still gives 4 waves/EU = 4 blocks/CU = our 1056/256 load.
// L1 prep split: inv5 on wave 0 (lanes 0-31), norm5 on wave 1 (lanes 64-95)
// so the two don't serialize under one wave's divergent EXEC mask.
// Bank audit unchanged from R7 (stride 9/25, all free).
// ---------------------------------------------------------------------------
__global__ __launch_bounds__(256, 2) void pairs_kernel(const float* __restrict__ k0,
                                                       const float* __restrict__ k1,
                                                       float* __restrict__ partial) {
    __shared__ __align__(16) float sA[800];  // L0: 64*9=576, L1: 32*25=800
    __shared__ __align__(16) float sB[800];
    int tid = threadIdx.x;
    float contrib = 0.0f;

    if (blockIdx.x < NB0) {
        // ---------------- layer 0: d=3, 64x64 ----------------
        int bi, bj;
        tri_decode(blockIdx.x, bi, bj);

        // prep: wave 0 inverts 64 row-mats, wave 1 normalizes 64 col-mats
        if (tid < 64) {
            inv3_to(k0 + (bi * 64 + tid) * 9, sA + tid * 9);
        } else if (tid < 128) {
            int j = tid - 64;
            norm3_to(k0 + (bj * 64 + j) * 9, sB + j * 9);
        }
        __syncthreads();

        int ti = tid >> 4, tj = tid & 15;
        int ibase = bi * 64 + ti * 4, jbase = bj * 64 + tj * 4;
        float a[4][9];
#pragma unroll
        for (int u = 0; u < 4; ++u)
#pragma unroll
            for (int e = 0; e < 9; ++e) a[u][e] = sA[(ti * 4 + u) * 9 + e];
#pragma unroll
        for (int v = 0; v < 4; ++v) {
            float b[9];
#pragma unroll
            for (int e = 0; e < 9; ++e) b[e] = sB[(tj * 4 + v) * 9 + e];
#pragma unroll
            for (int u = 0; u < 4; ++u) {
                float s = 0.0f;
#pragma unroll
                for (int r = 0; r < 3; ++r)
#pragma unroll
                    for (int c = 0; c < 3; ++c) {
                        float m = a[u][r * 3 + 0] * b[c];
                        m = fmaf(a[u][r * 3 + 1], b[3 + c], m);
                        m = fmaf(a[u][r * 3 + 2], b[6 + c], m);
                        float d = ((r == c) ? 1.0f : 0.0f) - m;
                        s = fmaf(d, d, s);
                    }
                bool take = ((ibase + u) > (jbase + v)) && (s < 1.0f);
                contrib += take ? (1.0f - __builtin_amdgcn_sqrtf(s)) : 0.0f;
            }
        }
    } else {
        // ---------------- layer 1: d=5, 32x32 ----------------
        int bi, bj;
        tri_decode(blockIdx.x - NB0, bi, bj);

        // prep: wave 0 (lanes 0-31) inverts, wave 1 (lanes 64-95) normalizes
        if (tid < 32) {
            inv5_to(k1 + (bi * 32 + tid) * 25, sA + tid * 25);
        } else if (tid >= 64 && tid < 96) {
            int j = tid - 64;
            norm5_to(k1 + (bj * 32 + j) * 25, sB + j * 25);
        }
        __syncthreads();

        int ti = tid >> 4, tj = tid & 15;
        int ibase = bi * 32 + ti * 2, jbase = bj * 32 + tj * 2;
        float a[2][25];
#pragma unroll
        for (int u = 0; u < 2; ++u)
#pragma unroll
            for (int e = 0; e < 25; ++e) a[u][e] = sA[(ti * 2 + u) * 25 + e];
#pragma unroll
        for (int v = 0; v < 2; ++v) {
            float b[25];
#pragma unroll
            for (int e = 0; e < 25; ++e) b[e] = sB[(tj * 2 + v) * 25 + e];
#pragma unroll
            for (int u = 0; u < 2; ++u) {
                float s = 0.0f;
#pragma unroll
                for (int r = 0; r < 5; ++r)
#pragma unroll
                    for (int c = 0; c < 5; ++c) {
                        float m = a[u][r * 5 + 0] * b[c];
#pragma unroll
                        for (int k = 1; k < 5; ++k) m = fmaf(a[u][r * 5 + k], b[k * 5 + c], m);
                        float d = ((r == c) ? 1.0f : 0.0f) - m;
                        s = fmaf(d, d, s);
                    }
                bool take = ((ibase + u) > (jbase + v)) && (s < 1.0f);
                contrib += take ? (1.0f - __builtin_amdgcn_sqrtf(s)) : 0.0f;
            }
        }
    }

    // block reduction -> one partial per block, distinct address (no contention)
#pragma unroll
    for (int off = 32; off; off >>= 1) contrib += __shfl_down(contrib, off);
    __shared__ float wsum[4];
    if ((tid & 63) == 0) wsum[tid >> 6] = contrib;
    __syncthreads();
    if (tid == 0) partial[blockIdx.x] = wsum[0] + wsum[1] + wsum[2] + wsum[3];
}

__global__ void finalize_kernel(const float* __restrict__ partial, float* __restrict__ out) {
    int tid = threadIdx.x;
    double s0 = 0.0, s1 = 0.0;
    for (int x = tid; x < NB0; x += 256) s0 += (double)partial[x];
    for (int x = NB0 + tid; x < NBTOT; x += 256) s1 += (double)partial[x];
#pragma unroll
    for (int off = 32; off; off >>= 1) {
        s0 += __shfl_down(s0, off);
        s1 += __shfl_down(s1, off);
    }
    __shared__ double w0[4], w1[4];
    if ((tid & 63) == 0) { w0[tid >> 6] = s0; w1[tid >> 6] = s1; }
    __syncthreads();
    if (tid == 0) {
        double S0 = w0[0] + w0[1] + w0[2] + w0[3];
        double S1 = w1[0] + w1[1] + w1[2] + w1[3];
        // final = (2*S0/(n0(n0-1)) + 2*S1/(n1(n1-1))) / 2
        double res = S0 / ((double)N0 * (double)(N0 - 1)) +
                     S1 / ((double)N1 * (double)(N1 - 1));
        out[0] = (float)res;
    }
}

extern "C" void kernel_launch(void* const* d_in, const int* in_sizes, int n_in,
                              void* d_out, int out_size, void* d_ws, size_t ws_size,
                              hipStream_t stream) {
    const float* k0 = (const float*)d_in[0];  // (2048,3,3)
    const float* k1 = (const float*)d_in[1];  // (1024,5,5)
    float* out = (float*)d_out;

    float* partial = (float*)d_ws;  // 1056 floats

    pairs_kernel<<<NBTOT, 256, 0, stream>>>(k0, k1, partial);
    finalize_kernel<<<1, 256, 0, stream>>>(partial, out);
}

// Round 11
// 65.013 us; speedup vs baseline: 1.0099x; 1.0099x over previous
//
#include <hip/hip_runtime.h>
#include <math.h>

#define N0 2048
#define N1 1024
#define M0T 32                     // 2048 / 64-row tiles
#define M1T 32                     // 1024 / 32-row tiles
#define NB0 (M0T * (M0T + 1) / 2)  // 528 lower-tri tile pairs, layer 0 (64x64)
#define NB1 (M1T * (M1T + 1) / 2)  // 528 lower-tri tile pairs, layer 1 (32x32)
#define NBTOT (NB0 + NB1)          // 1056 blocks

// ws layout (floats): partial[NBTOT] only.
//
// Ledger:
// R1: same-address atomics+fence serialize (never per-block RMW one address).
//     Counter relic: VGPR_Count=40 vs ~50-float live set.
// R2/R4: window = fill(39.5 fixed harness poison) + ~26us controllable.
//     Dispatch-count changes NET ZERO (boundaries ~= fused-prep cost).
// R7: un-split tiles + drop 5x5 Newton: 69.9 -> 65.4, absmax 0. pairs ~18us.
// R9: cooperative single-kernel FAILED absmax: plain stores not coherent
//     across XCDs despite fence+grid.sync. Kernel boundary IS the flush.
// R10: launch_bounds(256,2) + prep wave-split NET ZERO (65.65). Falsifies
//     "cap was the blocker": allocator holds 40 VGPR by SINKING the a-tile
//     preload into the loop as LDS re-reads (not a spill -> cap irrelevant).
//     => per-thread LDS ~180 b32 insts; LDS issue ~ FMA issue; explains the
//     2x gap between issue floor (~10us) and measured pairs (~18us).
// R11 (this): force the tiling: pad LDS strides 9->12, 25->28 (16B-aligned),
//     ds_read_b128 everywhere, sched_barrier(0) after a-preload pins loads
//     before the loop (values live across -> MUST get registers),
//     launch_bounds(256,4) caps at the 128-VGPR/4-waves-EU tier
//     (live set ~75 L0 / ~104 L1 fits). Else exact R7.
//     Predict 65.4 -> 60-63us, absmax 0.

__device__ __forceinline__ void tri_decode(int t, int& bi, int& bj) {
    int b = (int)((sqrtf(8.0f * t + 1.0f) - 1.0f) * 0.5f);
    while ((b + 1) * (b + 2) / 2 <= t) ++b;
    while (b * (b + 1) / 2 > t) --b;
    bi = b;
    bj = t - b * (b + 1) / 2;
}

// normalize + adjugate inverse + 1 Newton polish, 3x3, fp32
__device__ __forceinline__ void inv3_to(const float* __restrict__ g, float* __restrict__ dst) {
    float a[9];
    float ss = 0.0f;
#pragma unroll
    for (int e = 0; e < 9; ++e) { a[e] = g[e]; ss = fmaf(a[e], a[e], ss); }
    float rn = 1.0f / (sqrtf(ss) + 1e-8f);
#pragma unroll
    for (int e = 0; e < 9; ++e) a[e] *= rn;
    float c00 = a[4] * a[8] - a[5] * a[7];
    float c01 = -(a[3] * a[8] - a[5] * a[6]);
    float c02 = a[3] * a[7] - a[4] * a[6];
    float det = a[0] * c00 + a[1] * c01 + a[2] * c02;
    float id = 1.0f / det;
    float x[9];
    x[0] = c00 * id;
    x[1] = (a[2] * a[7] - a[1] * a[8]) * id;
    x[2] = (a[1] * a[5] - a[2] * a[4]) * id;
    x[3] = c01 * id;
    x[4] = (a[0] * a[8] - a[2] * a[6]) * id;
    x[5] = (a[2] * a[3] - a[0] * a[5]) * id;
    x[6] = c02 * id;
    x[7] = (a[1] * a[6] - a[0] * a[7]) * id;
    x[8] = (a[0] * a[4] - a[1] * a[3]) * id;
    // Newton polish: x <- x(2I - a x)
    float r[9];
#pragma unroll
    for (int i = 0; i < 3; ++i)
#pragma unroll
        for (int j = 0; j < 3; ++j) {
            float m = a[i * 3 + 0] * x[0 * 3 + j];
            m = fmaf(a[i * 3 + 1], x[1 * 3 + j], m);
            m = fmaf(a[i * 3 + 2], x[2 * 3 + j], m);
            r[i * 3 + j] = ((i == j) ? 2.0f : 0.0f) - m;
        }
#pragma unroll
    for (int i = 0; i < 3; ++i)
#pragma unroll
        for (int j = 0; j < 3; ++j) {
            float m = x[i * 3 + 0] * r[0 * 3 + j];
            m = fmaf(x[i * 3 + 1], r[1 * 3 + j], m);
            m = fmaf(x[i * 3 + 2], r[2 * 3 + j], m);
            dst[i * 3 + j] = m;
        }
}

// normalize only, 3x3
__device__ __forceinline__ void norm3_to(const float* __restrict__ g, float* __restrict__ dst) {
    float a[9];
    float ss = 0.0f;
#pragma unroll
    for (int e = 0; e < 9; ++e) { a[e] = g[e]; ss = fmaf(a[e], a[e], ss); }
    float rn = 1.0f / (sqrtf(ss) + 1e-8f);
#pragma unroll
    for (int e = 0; e < 9; ++e) dst[e] = a[e] * rn;
}

// normalize + branchless GJ w/ partial pivot, 5x5, fp32 (no Newton; R7-verified)
__device__ __forceinline__ void inv5_to(const float* __restrict__ g, float* __restrict__ dst) {
    float A[5][5], B[5][5];
    float ss = 0.0f;
#pragma unroll
    for (int r = 0; r < 5; ++r)
#pragma unroll
        for (int c = 0; c < 5; ++c) {
            float v = g[r * 5 + c];
            A[r][c] = v;
            ss = fmaf(v, v, ss);
        }
    float rn = 1.0f / (sqrtf(ss) + 1e-8f);
#pragma unroll
    for (int r = 0; r < 5; ++r)
#pragma unroll
        for (int c = 0; c < 5; ++c) {
            A[r][c] *= rn;
            B[r][c] = (r == c) ? 1.0f : 0.0f;
        }
#pragma unroll
    for (int k = 0; k < 5; ++k) {
#pragma unroll
        for (int r = k + 1; r < 5; ++r) {
            bool sw = fabsf(A[r][k]) > fabsf(A[k][k]);
#pragma unroll
            for (int c = k; c < 5; ++c) {
                float Ar = A[r][c], Ak = A[k][c];
                A[r][c] = sw ? Ak : Ar;
                A[k][c] = sw ? Ar : Ak;
            }
#pragma unroll
            for (int c = 0; c < 5; ++c) {
                float Br = B[r][c], Bk = B[k][c];
                B[r][c] = sw ? Bk : Br;
                B[k][c] = sw ? Br : Bk;
            }
        }
        float piv = 1.0f / A[k][k];
#pragma unroll
        for (int c = k; c < 5; ++c) A[k][c] *= piv;
#pragma unroll
        for (int c = 0; c < 5; ++c) B[k][c] *= piv;
#pragma unroll
        for (int r = 0; r < 5; ++r) {
            if (r == k) continue;
            float f = A[r][k];
#pragma unroll
            for (int c = k; c < 5; ++c) A[r][c] = fmaf(-f, A[k][c], A[r][c]);
#pragma unroll
            for (int c = 0; c < 5; ++c) B[r][c] = fmaf(-f, B[k][c], B[r][c]);
        }
    }
#pragma unroll
    for (int r = 0; r < 5; ++r)
#pragma unroll
        for (int c = 0; c < 5; ++c) dst[r * 5 + c] = B[r][c];
}

// normalize only, 5x5
__device__ __forceinline__ void norm5_to(const float* __restrict__ g, float* __restrict__ dst) {
    float a[25];
    float ss = 0.0f;
#pragma unroll
    for (int e = 0; e < 25; ++e) { a[e] = g[e]; ss = fmaf(a[e], a[e], ss); }
    float rn = 1.0f / (sqrtf(ss) + 1e-8f);
#pragma unroll
    for (int e = 0; e < 25; ++e) dst[e] = a[e] * rn;
}

// ---------------------------------------------------------------------------
// Fused prep + pair-distance kernel, full-tile triangular grid (R7 structure)
// with PADDED LDS (L0: [64][12], L1: [32][28]) + b128 reads + forced register
// residency of the a-tiles (sched_barrier after preload).
// Read-bank audit (64-lane wave, 32 banks):
//   L0 b: tj stride 12f -> quads {0-3,4-7,...,28-31} all distinct, 2-way; free
//   L1 b: tj stride 28f -> 8 distinct quads, 2-way; free
//   a-reads: broadcast within 16-lane tj groups, <=4 distinct quads; free
//   prep writes: scalar b32, stride 12/28 -> <=4-way on a tiny phase; ok
// ---------------------------------------------------------------------------
__global__ __launch_bounds__(256, 4) void pairs_kernel(const float* __restrict__ k0,
                                                       const float* __restrict__ k1,
                                                       float* __restrict__ partial) {
    __shared__ __align__(16) float sA[896];  // L0: 64*12=768, L1: 32*28=896
    __shared__ __align__(16) float sB[896];
    int tid = threadIdx.x;
    float contrib = 0.0f;

    if (blockIdx.x < NB0) {
        // ---------------- layer 0: d=3, 64x64, stride 12 ----------------
        int bi, bj;
        tri_decode(blockIdx.x, bi, bj);

        if (tid < 64) {
            inv3_to(k0 + (bi * 64 + tid) * 9, sA + tid * 12);
        } else if (tid < 128) {
            int j = tid - 64;
            norm3_to(k0 + (bj * 64 + j) * 9, sB + j * 12);
        }
        __syncthreads();

        int ti = tid >> 4, tj = tid & 15;
        int ibase = bi * 64 + ti * 4, jbase = bj * 64 + tj * 4;
        float a[4][12];
#pragma unroll
        for (int u = 0; u < 4; ++u) {
            float4* d = (float4*)a[u];
            const float4* s = (const float4*)(sA + (ti * 4 + u) * 12);
            d[0] = s[0]; d[1] = s[1]; d[2] = s[2];
        }
        __builtin_amdgcn_sched_barrier(0);  // pin preload: a[][] live across loop
#pragma unroll
        for (int v = 0; v < 4; ++v) {
            float b[12];
            {
                float4* d = (float4*)b;
                const float4* s = (const float4*)(sB + (tj * 4 + v) * 12);
                d[0] = s[0]; d[1] = s[1]; d[2] = s[2];
            }
#pragma unroll
            for (int u = 0; u < 4; ++u) {
                float s = 0.0f;
#pragma unroll
                for (int r = 0; r < 3; ++r)
#pragma unroll
                    for (int c = 0; c < 3; ++c) {
                        float m = a[u][r * 3 + 0] * b[c];
                        m = fmaf(a[u][r * 3 + 1], b[3 + c], m);
                        m = fmaf(a[u][r * 3 + 2], b[6 + c], m);
                        float d = ((r == c) ? 1.0f : 0.0f) - m;
                        s = fmaf(d, d, s);
                    }
                bool take = ((ibase + u) > (jbase + v)) && (s < 1.0f);
                contrib += take ? (1.0f - __builtin_amdgcn_sqrtf(s)) : 0.0f;
            }
        }
    } else {
        // ---------------- layer 1: d=5, 32x32, stride 28 ----------------
        int bi, bj;
        tri_decode(blockIdx.x - NB0, bi, bj);

        if (tid < 32) {
            inv5_to(k1 + (bi * 32 + tid) * 25, sA + tid * 28);
        } else if (tid < 64) {
            int j = tid - 32;
            norm5_to(k1 + (bj * 32 + j) * 25, sB + j * 28);
        }
        __syncthreads();

        int ti = tid >> 4, tj = tid & 15;
        int ibase = bi * 32 + ti * 2, jbase = bj * 32 + tj * 2;
        float a[2][28];
#pragma unroll
        for (int u = 0; u < 2; ++u) {
            float4* d = (float4*)a[u];
            const float4* s = (const float4*)(sA + (ti * 2 + u) * 28);
#pragma unroll
            for (int q = 0; q < 7; ++q) d[q] = s[q];
        }
        __builtin_amdgcn_sched_barrier(0);  // pin preload: a[][] live across loop
#pragma unroll
        for (int v = 0; v < 2; ++v) {
            float b[28];
            {
                float4* d = (float4*)b;
                const float4* s = (const float4*)(sB + (tj * 2 + v) * 28);
#pragma unroll
                for (int q = 0; q < 7; ++q) d[q] = s[q];
            }
#pragma unroll
            for (int u = 0; u < 2; ++u) {
                float s = 0.0f;
#pragma unroll
                for (int r = 0; r < 5; ++r)
#pragma unroll
                    for (int c = 0; c < 5; ++c) {
                        float m = a[u][r * 5 + 0] * b[c];
#pragma unroll
                        for (int k = 1; k < 5; ++k) m = fmaf(a[u][r * 5 + k], b[k * 5 + c], m);
                        float d = ((r == c) ? 1.0f : 0.0f) - m;
                        s = fmaf(d, d, s);
                    }
                bool take = ((ibase + u) > (jbase + v)) && (s < 1.0f);
                contrib += take ? (1.0f - __builtin_amdgcn_sqrtf(s)) : 0.0f;
            }
        }
    }

    // block reduction -> one partial per block, distinct address (no contention)
#pragma unroll
    for (int off = 32; off; off >>= 1) contrib += __shfl_down(contrib, off);
    __shared__ float wsum[4];
    if ((tid & 63) == 0) wsum[tid >> 6] = contrib;
    __syncthreads();
    if (tid == 0) partial[blockIdx.x] = wsum[0] + wsum[1] + wsum[2] + wsum[3];
}

__global__ void finalize_kernel(const float* __restrict__ partial, float* __restrict__ out) {
    int tid = threadIdx.x;
    double s0 = 0.0, s1 = 0.0;
    for (int x = tid; x < NB0; x += 256) s0 += (double)partial[x];
    for (int x = NB0 + tid; x < NBTOT; x += 256) s1 += (double)partial[x];
#pragma unroll
    for (int off = 32; off; off >>= 1) {
        s0 += __shfl_down(s0, off);
        s1 += __shfl_down(s1, off);
    }
    __shared__ double w0[4], w1[4];
    if ((tid & 63) == 0) { w0[tid >> 6] = s0; w1[tid >> 6] = s1; }
    __syncthreads();
    if (tid == 0) {
        double S0 = w0[0] + w0[1] + w0[2] + w0[3];
        double S1 = w1[0] + w1[1] + w1[2] + w1[3];
        // final = (2*S0/(n0(n0-1)) + 2*S1/(n1(n1-1))) / 2
        double res = S0 / ((double)N0 * (double)(N0 - 1)) +
                     S1 / ((double)N1 * (double)(N1 - 1));
        out[0] = (float)res;
    }
}

extern "C" void kernel_launch(void* const* d_in, const int* in_sizes, int n_in,
                              void* d_out, int out_size, void* d_ws, size_t ws_size,
                              hipStream_t stream) {
    const float* k0 = (const float*)d_in[0];  // (2048,3,3)
    const float* k1 = (const float*)d_in[1];  // (1024,5,5)
    float* out = (float*)d_out;

    float* partial = (float*)d_ws;  // 1056 floats

    pairs_kernel<<<NBTOT, 256, 0, stream>>>(k0, k1, partial);
    finalize_kernel<<<1, 256, 0, stream>>>(partial, out);
}